// Round 9
// baseline (167.488 us; speedup 1.0000x reference)
//
#include <hip/hip_runtime.h>

typedef _Float16 f16;
typedef _Float16 f16x8 __attribute__((ext_vector_type(8)));
typedef _Float16 f16x4 __attribute__((ext_vector_type(4)));
typedef float f32x4 __attribute__((ext_vector_type(4)));

#define MFMA16(a, b, c) __builtin_amdgcn_mfma_f32_16x16x32_f16((a), (b), (c), 0, 0, 0)

typedef __attribute__((address_space(3))) void lds_void;
typedef const __attribute__((address_space(1))) void g_void;
__device__ __forceinline__ void async_copy16(void* lds, const void* g) {
    __builtin_amdgcn_global_load_lds((g_void*)g, (lds_void*)lds, 16, 0, 0);
}

// ---------------------------------------------------------------------------
// fp32 -> fp16 conversion (x)
__global__ void cvt_x(const float* __restrict__ in, f16* __restrict__ out, int n) {
    int i4 = (blockIdx.x * 256 + threadIdx.x) * 4;
    if (i4 >= n) return;
    float4 v = *reinterpret_cast<const float4*>(in + i4);
    f16x4 o;
    o[0] = (f16)v.x; o[1] = (f16)v.y; o[2] = (f16)v.z; o[3] = (f16)v.w;
    *reinterpret_cast<f16x4*>(out + i4) = o;
}

// ---------------------------------------------------------------------------
// transpose fp32 [K][N] -> fp16 [N][K]   (K,N multiples of 64)
__global__ void wtrans(const float* __restrict__ in, f16* __restrict__ out, int K, int N) {
    __shared__ f16 tile[64][65];
    int n0 = blockIdx.x * 64, k0 = blockIdx.y * 64;
    int c = threadIdx.x & 63, rb = threadIdx.x >> 6;
#pragma unroll
    for (int it = 0; it < 16; ++it) {
        int r = rb + it * 4;
        tile[r][c] = (f16)in[(size_t)(k0 + r) * N + n0 + c];
    }
    __syncthreads();
#pragma unroll
    for (int it = 0; it < 16; ++it) {
        int rr = rb + it * 4;
        out[(size_t)(n0 + rr) * K + k0 + c] = tile[c][rr];
    }
}

// ---------------------------------------------------------------------------
// m97-structure GEMM: C[M][N] = A[M][K] @ Bt[N][K]^T + bias.
// 1D grid with XCD-chunked tile order (same-A-panel tiles share an XCD's L2).
#define BM 128
#define BN 128
#define BKK 32
__global__ __launch_bounds__(256) void gemm_tile(
    const f16* __restrict__ A, const f16* __restrict__ Bt,
    const float* __restrict__ bias, f16* __restrict__ Ch, float* __restrict__ Cf,
    int M, int N, int K, int nbx) {
    __shared__ f16 lA[2][BM * BKK];
    __shared__ f16 lB[2][BN * BKK];
    int tid = threadIdx.x;
    int lane = tid & 63, w = tid >> 6;
    int lr = lane & 15, lg = lane >> 4;
    int wm = (w & 1) * 64, wn = (w >> 1) * 64;

    int nwg = gridDim.x, wg = blockIdx.x;
    int tile = ((nwg & 7) == 0) ? ((wg & 7) * (nwg >> 3) + (wg >> 3)) : wg;
    int by = tile / nbx, bx = tile % nbx;

    int srow = tid >> 2;
    int scol = (tid & 3) * 8;
    const f16* ga0 = A  + (size_t)min(by * BM + srow,      M - 1) * K + scol;
    const f16* ga1 = A  + (size_t)min(by * BM + 64 + srow, M - 1) * K + scol;
    const f16* gb0 = Bt + (size_t)min(bx * BN + srow,      N - 1) * K + scol;
    const f16* gb1 = Bt + (size_t)min(bx * BN + 64 + srow, N - 1) * K + scol;

    f32x4 acc[4][4] = {};
    int NT = K / BKK;

#define STAGE(curb, kt) do {                                        \
        int ko = (kt) * BKK;                                        \
        async_copy16(&lA[curb][w * 512],        ga0 + ko);          \
        async_copy16(&lA[curb][2048 + w * 512], ga1 + ko);          \
        async_copy16(&lB[curb][w * 512],        gb0 + ko);          \
        async_copy16(&lB[curb][2048 + w * 512], gb1 + ko);          \
    } while (0)

    STAGE(0, 0);
    __syncthreads();
    int cur = 0;
    for (int kt = 0; kt < NT; ++kt) {
        if (kt + 1 < NT) STAGE(cur ^ 1, kt + 1);
        f16x8 af[4], bf[4];
#pragma unroll
        for (int i = 0; i < 4; ++i) {
            af[i] = *reinterpret_cast<const f16x8*>(&lA[cur][(wm + i * 16 + lr) * BKK + lg * 8]);
            bf[i] = *reinterpret_cast<const f16x8*>(&lB[cur][(wn + i * 16 + lr) * BKK + lg * 8]);
        }
#pragma unroll
        for (int mi = 0; mi < 4; ++mi)
#pragma unroll
            for (int ni = 0; ni < 4; ++ni)
                acc[mi][ni] = MFMA16(af[mi], bf[ni], acc[mi][ni]);
        __syncthreads();
        cur ^= 1;
    }
#undef STAGE

#pragma unroll
    for (int mi = 0; mi < 4; ++mi) {
#pragma unroll
        for (int ni = 0; ni < 4; ++ni) {
            int col = bx * BN + wn + ni * 16 + lr;
            float bv = bias ? bias[col] : 0.f;
#pragma unroll
            for (int r = 0; r < 4; ++r) {
                int row = by * BM + wm + mi * 16 + 4 * lg + r;
                if (row >= M) continue;
                float v = acc[mi][ni][r] + bv;
                if (Ch) Ch[(size_t)row * N + col] = (f16)v;
                else    Cf[(size_t)row * N + col] = v;
            }
        }
    }
}

// ---------------------------------------------------------------------------
// RoPE on q,k halves of qkv -> head-major padded layout [(b*16+h)*Spad+pos][64].
// Q is pre-scaled by 1/sqrt(DH)=0.125 (qh2 feeds only the attention kernel).
__global__ void rope_qk(const f16* __restrict__ qkv, const int* __restrict__ cu,
                        int Bn, int T, int Spad,
                        f16* __restrict__ qh2, f16* __restrict__ kh2) {
    int idx = blockIdx.x * 256 + threadIdx.x;
    if (idx >= T * 512) return;
    int i = idx & 31;
    int hh = (idx >> 5) & 15;
    int t = idx >> 9;
    int b = 0, pos = t;
    for (int q = 0; q < Bn; ++q) {
        int lo = cu[q], hi = cu[q + 1];
        if (t >= lo && t < hi) { b = q; pos = t - lo; break; }
    }
    float inv = exp2f((float)i * (-13.287712379549449f / 32.f));
    float ang = (float)pos * inv;
    float sn, cs;
    __sincosf(ang, &sn, &cs);
    size_t base = (size_t)t * 3072 + hh * 64 + i;
    float q1 = (float)qkv[base],        q2 = (float)qkv[base + 32];
    float k1 = (float)qkv[base + 1024], k2 = (float)qkv[base + 1056];
    size_t ob = ((size_t)(b * 16 + hh) * Spad + pos) * 64 + i;
    qh2[ob]      = (f16)((q1 * cs - q2 * sn) * 0.125f);
    qh2[ob + 32] = (f16)((q2 * cs + q1 * sn) * 0.125f);
    kh2[ob]      = (f16)(k1 * cs - k2 * sn);
    kh2[ob + 32] = (f16)(k2 * cs + k1 * sn);
}

// ---------------------------------------------------------------------------
// Scatter V into per-(b,h) transposed layout vt[b][h][d][pos], pos-contiguous.
__global__ void v_trans(const f16* __restrict__ qkv, const int* __restrict__ cu,
                        int Bn, int T, int Spad, f16* __restrict__ vt) {
    __shared__ f16 tile[64][65];
    int h = blockIdx.y;
    int t0 = blockIdx.x * 64;
    int c = threadIdx.x & 63, rb = threadIdx.x >> 6;
#pragma unroll
    for (int it = 0; it < 16; ++it) {
        int r = rb + it * 4;
        int t = t0 + r;
        f16 v = (f16)0.f;
        if (t < T) v = qkv[(size_t)t * 3072 + 2048 + h * 64 + c];
        tile[r][c] = v;
    }
    __syncthreads();
    int t = t0 + c;
    int bb = 0, pos = -1;
    if (t < T) {
        for (int q = 0; q < Bn; ++q) {
            int lo = cu[q], hi = cu[q + 1];
            if (t >= lo && t < hi) { bb = q; pos = t - lo; }
        }
    }
#pragma unroll
    for (int it = 0; it < 16; ++it) {
        int d = rb + it * 4;
        if (pos >= 0) vt[((size_t)(bb * 16 + h) * 64 + d) * Spad + pos] = tile[c][d];
    }
}

// ---------------------------------------------------------------------------
// Flash attention v5: verified round-7 structure, extended 1-wave kernel:
// QBLK=64 (4 q-tiles per wave, pure replication of verified qt pattern),
// KVBLK=32 unchanged, K register double-buffer (next K issued right after
// QK^T), Q pre-scaled. 1D grid with bijective XCD-affinity remap.
__global__ __launch_bounds__(64) void attn_fwd(
    const f16* __restrict__ qh2, const f16* __restrict__ kh2,
    const f16* __restrict__ vt, const int* __restrict__ cu,
    f16* __restrict__ oh, int Spad, int nq, int Bn) {
    int wgid = blockIdx.x;
    int nbh = Bn * 16;
    int b, h, qi;
    if ((nbh & 7) == 0) {
        int xcd = wgid & 7, rest = wgid >> 3, nbh8 = nbh >> 3;
        int bhhi = rest % nbh8;
        qi = (nq - 1) - rest / nbh8;          // longest blocks first
        int bhv = (bhhi << 3) | xcd;
        b = bhv >> 4; h = bhv & 15;
    } else {
        qi = wgid % nq;
        int bhv = wgid / nq;
        b = bhv >> 4; h = bhv & 15;
    }
    int bh = b * 16 + h;
    int s0 = cu[b];
    int len = cu[b + 1] - s0;
    int q0 = qi * 64;
    if (q0 >= len) return;
    int lane = threadIdx.x & 63, lr = lane & 15, lg = lane >> 4;
    __shared__ f16 pl[4][16][40];   // [qt][q-row][k(32) padded to 40]

    const f16* qbase = qh2 + (size_t)bh * Spad * 64;
    const f16* kbase = kh2 + (size_t)bh * Spad * 64;
    const f16* vbase = vt  + (size_t)bh * 64 * Spad;

    f16x8 qf[4][2];
#pragma unroll
    for (int qt = 0; qt < 4; ++qt) {
        const f16* qp = qbase + (size_t)(q0 + 16 * qt + lr) * 64 + 8 * lg;
        qf[qt][0] = *reinterpret_cast<const f16x8*>(qp);
        qf[qt][1] = *reinterpret_cast<const f16x8*>(qp + 32);
    }
    float mrun[4] = {-1e30f, -1e30f, -1e30f, -1e30f};
    float lrun[4] = {0.f, 0.f, 0.f, 0.f};
    f32x4 oacc[4][4] = {};   // [qt][dt]: row = d_local = 4*lg+r, col = q = lr

    int kend = min(q0 + 64, len);
    int ntk = (kend + 31) >> 5;

    // K register double-buffer: preload tile 0
    f16x8 kf[2][2], kn[2][2];
#pragma unroll
    for (int j = 0; j < 2; ++j) {
        const f16* kp = kbase + (size_t)(16 * j + lr) * 64 + 8 * lg;
        kf[j][0] = *reinterpret_cast<const f16x8*>(kp);
        kf[j][1] = *reinterpret_cast<const f16x8*>(kp + 32);
    }

    for (int kt = 0; kt < ntk; ++kt) {
        int kk0 = kt << 5;
        // S^T tiles from current K: D[row=k_local=4lg+r][col=q=lr]
        f32x4 st[4][2];
#pragma unroll
        for (int qt = 0; qt < 4; ++qt)
#pragma unroll
            for (int j = 0; j < 2; ++j) {
                f32x4 z = {0, 0, 0, 0};
                z = MFMA16(kf[j][0], qf[qt][0], z);
                z = MFMA16(kf[j][1], qf[qt][1], z);
                st[qt][j] = z;
            }
        // prefetch next K tile (hides L2 latency under softmax + PV)
        if (kt + 1 < ntk) {
#pragma unroll
            for (int j = 0; j < 2; ++j) {
                const f16* kp = kbase + (size_t)(kk0 + 32 + 16 * j + lr) * 64 + 8 * lg;
                kn[j][0] = *reinterpret_cast<const f16x8*>(kp);
                kn[j][1] = *reinterpret_cast<const f16x8*>(kp + 32);
            }
        }
        // online softmax per q-tile (independent chains -> ILP)
#pragma unroll
        for (int qt = 0; qt < 4; ++qt) {
            int qr = q0 + 16 * qt + lr;
            float sv[2][4];
            float mx = -1e30f;
#pragma unroll
            for (int j = 0; j < 2; ++j)
#pragma unroll
                for (int r = 0; r < 4; ++r) {
                    int kc = kk0 + 16 * j + 4 * lg + r;
                    float v = st[qt][j][r];
                    if (kc > qr || kc >= len) v = -1e30f;
                    sv[j][r] = v;
                    mx = fmaxf(mx, v);
                }
            mx = fmaxf(mx, __shfl_xor(mx, 16, 64));
            mx = fmaxf(mx, __shfl_xor(mx, 32, 64));
            float mnew = fmaxf(mrun[qt], mx);
            float al = __expf(mrun[qt] - mnew);
            mrun[qt] = mnew;
            float rs = 0.f;
            f16x4 pk0, pk1;
#pragma unroll
            for (int r = 0; r < 4; ++r) {
                float p0 = __expf(sv[0][r] - mnew);
                float p1 = __expf(sv[1][r] - mnew);
                rs += p0 + p1;
                pk0[r] = (f16)p0;
                pk1[r] = (f16)p1;
            }
            rs += __shfl_xor(rs, 16, 64);
            rs += __shfl_xor(rs, 32, 64);
            lrun[qt] = lrun[qt] * al + rs;
            *reinterpret_cast<f16x4*>(&pl[qt][lr][4 * lg])      = pk0;
            *reinterpret_cast<f16x4*>(&pl[qt][lr][16 + 4 * lg]) = pk1;
#pragma unroll
            for (int dt = 0; dt < 4; ++dt)
#pragma unroll
                for (int r = 0; r < 4; ++r) oacc[qt][dt][r] *= al;
        }
        __syncthreads();
        f16x8 pa[4];
#pragma unroll
        for (int qt = 0; qt < 4; ++qt)
            pa[qt] = *reinterpret_cast<const f16x8*>(&pl[qt][lr][8 * lg]);
#pragma unroll
        for (int dt = 0; dt < 4; ++dt) {
            f16x8 vf = *reinterpret_cast<const f16x8*>(vbase + (size_t)(16 * dt + lr) * Spad + kk0 + 8 * lg);
#pragma unroll
            for (int qt = 0; qt < 4; ++qt)
                oacc[qt][dt] = MFMA16(vf, pa[qt], oacc[qt][dt]);
        }
        __syncthreads();
        // rotate K double-buffer
#pragma unroll
        for (int j = 0; j < 2; ++j) {
            kf[j][0] = kn[j][0];
            kf[j][1] = kn[j][1];
        }
    }
    // store: O[q=lr][d=16dt+4lg+r], vectorized 8B per (qt,dt)
#pragma unroll
    for (int qt = 0; qt < 4; ++qt) {
        int qr = q0 + 16 * qt + lr;
        if (qr >= len) continue;
        float linv = 1.f / lrun[qt];
        f16* orow = oh + (size_t)(s0 + qr) * 1024 + h * 64;
#pragma unroll
        for (int dt = 0; dt < 4; ++dt) {
            f16x4 ov;
#pragma unroll
            for (int r = 0; r < 4; ++r) ov[r] = (f16)(oacc[qt][dt][r] * linv);
            *reinterpret_cast<f16x4*>(orow + 16 * dt + 4 * lg) = ov;
        }
    }
}

// ---------------------------------------------------------------------------
extern "C" void kernel_launch(void* const* d_in, const int* in_sizes, int n_in,
                              void* d_out, int out_size, void* d_ws, size_t ws_size,
                              hipStream_t stream) {
    const float* x    = (const float*)d_in[0];
    const float* Wqkv = (const float*)d_in[1];
    const float* bqkv = (const float*)d_in[2];
    const float* Wo   = (const float*)d_in[3];
    const float* bo   = (const float*)d_in[4];
    const int*   cu   = (const int*)d_in[5];

    const int Dm = 1024;
    int T  = in_sizes[0] / Dm;
    int Bn = in_sizes[5] - 1;
    int Spad = 1024;  // max_seqlen

    auto al = [](size_t v) { return (v + 255) & ~(size_t)255; };
    char* w = (char*)d_ws;
    size_t off = 0;
    f16* xh     = (f16*)(w + off); off = al(off + (size_t)2 * T * 1024);
    f16* qkvh   = (f16*)(w + off); off = al(off + (size_t)2 * T * 3072);
    f16* wqkvT  = (f16*)(w + off); off = al(off + (size_t)2 * 3072 * 1024);
    f16* woT    = (f16*)(w + off); off = al(off + (size_t)2 * 1024 * 1024);
    f16* qh2    = (f16*)(w + off); off = al(off + (size_t)2 * Bn * 16 * 64 * (size_t)Spad);
    f16* kh2    = (f16*)(w + off); off = al(off + (size_t)2 * Bn * 16 * 64 * (size_t)Spad);
    f16* vtp    = (f16*)(w + off); off = al(off + (size_t)2 * Bn * 16 * 64 * (size_t)Spad);
    f16* ohp    = (f16*)(w + off); off = al(off + (size_t)2 * T * 1024);
    (void)ws_size;

    {
        int n = T * 1024;
        cvt_x<<<(n / 4 + 255) / 256, 256, 0, stream>>>(x, xh, n);
    }
    wtrans<<<dim3(3072 / 64, 1024 / 64), 256, 0, stream>>>(Wqkv, wqkvT, 1024, 3072);
    wtrans<<<dim3(1024 / 64, 1024 / 64), 256, 0, stream>>>(Wo, woT, 1024, 1024);
    {
        int nbx = 3072 / BN, nby = (T + BM - 1) / BM;
        gemm_tile<<<nbx * nby, 256, 0, stream>>>(xh, wqkvT, bqkv, qkvh, nullptr, T, 3072, 1024, nbx);
    }
    {
        int total = T * 512;
        rope_qk<<<(total + 255) / 256, 256, 0, stream>>>(qkvh, cu, Bn, T, Spad, qh2, kh2);
    }
    v_trans<<<dim3((T + 63) / 64, 16), 256, 0, stream>>>(qkvh, cu, Bn, T, Spad, vtp);
    {
        int nq = Spad / 64;
        int ngrid = nq * 16 * Bn;
        attn_fwd<<<ngrid, 64, 0, stream>>>(qh2, kh2, vtp, cu, ohp, Spad, nq, Bn);
    }
    {
        int nbx = 1024 / BN, nby = (T + BM - 1) / BM;
        gemm_tile<<<nbx * nby, 256, 0, stream>>>(ohp, woT, bo, nullptr, (float*)d_out, T, 1024, 1024, nbx);
    }
}

// Round 10
// 138.829 us; speedup vs baseline: 1.2064x; 1.2064x over previous
//
#include <hip/hip_runtime.h>

typedef _Float16 f16;
typedef _Float16 f16x8 __attribute__((ext_vector_type(8)));
typedef _Float16 f16x4 __attribute__((ext_vector_type(4)));
typedef float f32x4 __attribute__((ext_vector_type(4)));

#define MFMA16(a, b, c) __builtin_amdgcn_mfma_f32_16x16x32_f16((a), (b), (c), 0, 0, 0)

typedef __attribute__((address_space(3))) void lds_void;
typedef const __attribute__((address_space(1))) void g_void;
__device__ __forceinline__ void async_copy16(void* lds, const void* g) {
    __builtin_amdgcn_global_load_lds((g_void*)g, (lds_void*)lds, 16, 0, 0);
}

// ---------------------------------------------------------------------------
// fp32 -> fp16 conversion (x)
__global__ void cvt_x(const float* __restrict__ in, f16* __restrict__ out, int n) {
    int i4 = (blockIdx.x * 256 + threadIdx.x) * 4;
    if (i4 >= n) return;
    float4 v = *reinterpret_cast<const float4*>(in + i4);
    f16x4 o;
    o[0] = (f16)v.x; o[1] = (f16)v.y; o[2] = (f16)v.z; o[3] = (f16)v.w;
    *reinterpret_cast<f16x4*>(out + i4) = o;
}

// ---------------------------------------------------------------------------
// merged transpose of BOTH weight matrices: fp32 [K][N] -> fp16 [N][K]
// blocks 0..767: Wqkv (1024x3072); blocks 768..1023: Wo (1024x1024)
__global__ void wtrans2(const float* __restrict__ Wqkv, const float* __restrict__ Wo,
                        f16* __restrict__ outQkv, f16* __restrict__ outWo) {
    __shared__ f16 tile[64][65];
    int id = blockIdx.x;
    const float* in; f16* out; int N, bx, by;
    if (id < 768) { in = Wqkv; out = outQkv; N = 3072; bx = id % 48; by = id / 48; }
    else { id -= 768; in = Wo; out = outWo; N = 1024; bx = id % 16; by = id / 16; }
    const int K = 1024;
    int n0 = bx * 64, k0 = by * 64;
    int c = threadIdx.x & 63, rb = threadIdx.x >> 6;
#pragma unroll
    for (int it = 0; it < 16; ++it) {
        int r = rb + it * 4;
        tile[r][c] = (f16)in[(size_t)(k0 + r) * N + n0 + c];
    }
    __syncthreads();
#pragma unroll
    for (int it = 0; it < 16; ++it) {
        int rr = rb + it * 4;
        out[(size_t)(n0 + rr) * K + k0 + c] = tile[c][rr];
    }
}

// ---------------------------------------------------------------------------
// m97-structure GEMM: C[M][N] = A[M][K] @ Bt[N][K]^T + bias.
// 1D grid with XCD-chunked tile order (same-A-panel tiles share an XCD's L2).
#define BM 128
#define BN 128
#define BKK 32
__global__ __launch_bounds__(256) void gemm_tile(
    const f16* __restrict__ A, const f16* __restrict__ Bt,
    const float* __restrict__ bias, f16* __restrict__ Ch, float* __restrict__ Cf,
    int M, int N, int K, int nbx) {
    __shared__ f16 lA[2][BM * BKK];
    __shared__ f16 lB[2][BN * BKK];
    int tid = threadIdx.x;
    int lane = tid & 63, w = tid >> 6;
    int lr = lane & 15, lg = lane >> 4;
    int wm = (w & 1) * 64, wn = (w >> 1) * 64;

    int nwg = gridDim.x, wg = blockIdx.x;
    int tile = ((nwg & 7) == 0) ? ((wg & 7) * (nwg >> 3) + (wg >> 3)) : wg;
    int by = tile / nbx, bx = tile % nbx;

    int srow = tid >> 2;
    int scol = (tid & 3) * 8;
    const f16* ga0 = A  + (size_t)min(by * BM + srow,      M - 1) * K + scol;
    const f16* ga1 = A  + (size_t)min(by * BM + 64 + srow, M - 1) * K + scol;
    const f16* gb0 = Bt + (size_t)min(bx * BN + srow,      N - 1) * K + scol;
    const f16* gb1 = Bt + (size_t)min(bx * BN + 64 + srow, N - 1) * K + scol;

    f32x4 acc[4][4] = {};
    int NT = K / BKK;

#define STAGE(curb, kt) do {                                        \
        int ko = (kt) * BKK;                                        \
        async_copy16(&lA[curb][w * 512],        ga0 + ko);          \
        async_copy16(&lA[curb][2048 + w * 512], ga1 + ko);          \
        async_copy16(&lB[curb][w * 512],        gb0 + ko);          \
        async_copy16(&lB[curb][2048 + w * 512], gb1 + ko);          \
    } while (0)

    STAGE(0, 0);
    __syncthreads();
    int cur = 0;
    for (int kt = 0; kt < NT; ++kt) {
        if (kt + 1 < NT) STAGE(cur ^ 1, kt + 1);
        f16x8 af[4], bf[4];
#pragma unroll
        for (int i = 0; i < 4; ++i) {
            af[i] = *reinterpret_cast<const f16x8*>(&lA[cur][(wm + i * 16 + lr) * BKK + lg * 8]);
            bf[i] = *reinterpret_cast<const f16x8*>(&lB[cur][(wn + i * 16 + lr) * BKK + lg * 8]);
        }
#pragma unroll
        for (int mi = 0; mi < 4; ++mi)
#pragma unroll
            for (int ni = 0; ni < 4; ++ni)
                acc[mi][ni] = MFMA16(af[mi], bf[ni], acc[mi][ni]);
        __syncthreads();
        cur ^= 1;
    }
#undef STAGE

#pragma unroll
    for (int mi = 0; mi < 4; ++mi) {
#pragma unroll
        for (int ni = 0; ni < 4; ++ni) {
            int col = bx * BN + wn + ni * 16 + lr;
            float bv = bias ? bias[col] : 0.f;
#pragma unroll
            for (int r = 0; r < 4; ++r) {
                int row = by * BM + wm + mi * 16 + 4 * lg + r;
                if (row >= M) continue;
                float v = acc[mi][ni][r] + bv;
                if (Ch) Ch[(size_t)row * N + col] = (f16)v;
                else    Cf[(size_t)row * N + col] = v;
            }
        }
    }
}

// ---------------------------------------------------------------------------
// Fused RoPE (q,k -> head-major, Q pre-scaled by 0.125) + V transpose
// (vt[b][h][d][pos]).  One block per (64 tokens, head).
__global__ __launch_bounds__(256) void rope_v(
    const f16* __restrict__ qkv, const int* __restrict__ cu,
    int Bn, int T, int Spad,
    f16* __restrict__ qh2, f16* __restrict__ kh2, f16* __restrict__ vt) {
    __shared__ f16 tile[64][65];
    int h = blockIdx.y;
    int t0 = blockIdx.x * 64;
    int tid = threadIdx.x;
    int c = tid & 63, rb = tid >> 6;
    // V tile load: tile[token][dim]
#pragma unroll
    for (int it = 0; it < 16; ++it) {
        int r = rb + it * 4;
        int t = t0 + r;
        f16 v = (f16)0.f;
        if (t < T) v = qkv[(size_t)t * 3072 + 2048 + h * 64 + c];
        tile[r][c] = v;
    }
    // RoPE: thread handles token t0+(tid>>2), dim group g = tid&3 (dims g*8..+7, +32)
    int tok = t0 + (tid >> 2);
    int g = tid & 3;
    if (tok < T) {
        int b = 0, pos = tok;
        for (int q = 0; q < Bn; ++q) {
            int lo = cu[q], hi = cu[q + 1];
            if (tok >= lo && tok < hi) { b = q; pos = tok - lo; break; }
        }
        const f16* qp = qkv + (size_t)tok * 3072 + h * 64 + g * 8;
        f16x8 q1 = *reinterpret_cast<const f16x8*>(qp);
        f16x8 q2 = *reinterpret_cast<const f16x8*>(qp + 32);
        f16x8 k1 = *reinterpret_cast<const f16x8*>(qp + 1024);
        f16x8 k2 = *reinterpret_cast<const f16x8*>(qp + 1056);
        f16x8 qo1, qo2, ko1, ko2;
#pragma unroll
        for (int e = 0; e < 8; ++e) {
            int i = g * 8 + e;
            float inv = exp2f((float)i * (-13.287712379549449f / 32.f));
            float ang = (float)pos * inv;
            float sn, cs;
            __sincosf(ang, &sn, &cs);
            float a = (float)q1[e], bq = (float)q2[e];
            float ka = (float)k1[e], kb = (float)k2[e];
            qo1[e] = (f16)((a * cs - bq * sn) * 0.125f);
            qo2[e] = (f16)((bq * cs + a * sn) * 0.125f);
            ko1[e] = (f16)(ka * cs - kb * sn);
            ko2[e] = (f16)(kb * cs + ka * sn);
        }
        size_t ob = ((size_t)(b * 16 + h) * Spad + pos) * 64 + g * 8;
        *reinterpret_cast<f16x8*>(qh2 + ob)      = qo1;
        *reinterpret_cast<f16x8*>(qh2 + ob + 32) = qo2;
        *reinterpret_cast<f16x8*>(kh2 + ob)      = ko1;
        *reinterpret_cast<f16x8*>(kh2 + ob + 32) = ko2;
    }
    __syncthreads();
    // V scatter: thread's token = t0 + c
    int t = t0 + c;
    int bb = 0, pos2 = -1;
    if (t < T) {
        for (int q = 0; q < Bn; ++q) {
            int lo = cu[q], hi = cu[q + 1];
            if (t >= lo && t < hi) { bb = q; pos2 = t - lo; }
        }
    }
#pragma unroll
    for (int it = 0; it < 16; ++it) {
        int d = rb + it * 4;
        if (pos2 >= 0) vt[((size_t)(bb * 16 + h) * 64 + d) * Spad + pos2] = tile[c][d];
    }
}

// ---------------------------------------------------------------------------
// Flash attention: round-7-verified structure (1 wave, QBLK=32, KVBLK=32,
// swapped-operand MFMA, lane-local softmax, P LDS round-trip with barriers,
// bijective XCD-affinity remap, longest-first). Deltas (r8-validated math):
// Q pre-scaled in rope (no *0.125 here), K register double-buffer, V-tile
// register prefetch issued before softmax.
__global__ __launch_bounds__(64) void attn_fwd(
    const f16* __restrict__ qh2, const f16* __restrict__ kh2,
    const f16* __restrict__ vt, const int* __restrict__ cu,
    f16* __restrict__ oh, int Spad, int nq, int Bn) {
    int wgid = blockIdx.x;
    int nbh = Bn * 16;
    int b, h, qi;
    if ((nbh & 7) == 0) {
        int xcd = wgid & 7, rest = wgid >> 3, nbh8 = nbh >> 3;
        int bhhi = rest % nbh8;
        qi = (nq - 1) - rest / nbh8;          // longest blocks first
        int bhv = (bhhi << 3) | xcd;
        b = bhv >> 4; h = bhv & 15;
    } else {
        qi = wgid % nq;
        int bhv = wgid / nq;
        b = bhv >> 4; h = bhv & 15;
    }
    int bh = b * 16 + h;
    int s0 = cu[b];
    int len = cu[b + 1] - s0;
    int q0 = qi * 32;
    if (q0 >= len) return;
    int lane = threadIdx.x & 63, lr = lane & 15, lg = lane >> 4;
    __shared__ f16 pl[2][16][40];   // [qt][q-row][k(32) padded to 40]

    const f16* qbase = qh2 + (size_t)bh * Spad * 64;
    const f16* kbase = kh2 + (size_t)bh * Spad * 64;
    const f16* vbase = vt  + (size_t)bh * 64 * Spad;

    f16x8 qf[2][2];
#pragma unroll
    for (int qt = 0; qt < 2; ++qt) {
        const f16* qp = qbase + (size_t)(q0 + 16 * qt + lr) * 64 + 8 * lg;
        qf[qt][0] = *reinterpret_cast<const f16x8*>(qp);
        qf[qt][1] = *reinterpret_cast<const f16x8*>(qp + 32);
    }
    float mrun[2] = {-1e30f, -1e30f}, lrun[2] = {0.f, 0.f};
    f32x4 oacc[2][4] = {};   // [qt][dt]: row = d_local = 4*lg+r, col = q = lr

    int kend = min(q0 + 32, len);
    int ntk = (kend + 31) >> 5;

    // K register double-buffer: preload tile 0 (addresses verbatim r7)
    f16x8 kf[2][2], kn[2][2];
#pragma unroll
    for (int j = 0; j < 2; ++j) {
        const f16* kp = kbase + (size_t)(16 * j + lr) * 64 + 8 * lg;
        kf[j][0] = *reinterpret_cast<const f16x8*>(kp);
        kf[j][1] = *reinterpret_cast<const f16x8*>(kp + 32);
    }

    for (int kt = 0; kt < ntk; ++kt) {
        int kk0 = kt << 5;
        // V prefetch for this tile (independent of softmax; hides L2 latency)
        f16x8 vf[4];
#pragma unroll
        for (int dt = 0; dt < 4; ++dt)
            vf[dt] = *reinterpret_cast<const f16x8*>(
                vbase + (size_t)(16 * dt + lr) * Spad + kk0 + 8 * lg);
        // S^T tiles: D[row=k_local=4lg+r][col=q=lr]
        f32x4 st[2][2];
#pragma unroll
        for (int qt = 0; qt < 2; ++qt)
#pragma unroll
            for (int j = 0; j < 2; ++j) {
                f32x4 z = {0, 0, 0, 0};
                z = MFMA16(kf[j][0], qf[qt][0], z);
                z = MFMA16(kf[j][1], qf[qt][1], z);
                st[qt][j] = z;
            }
        // prefetch next K tile
        if (kt + 1 < ntk) {
#pragma unroll
            for (int j = 0; j < 2; ++j) {
                const f16* kp = kbase + (size_t)(kk0 + 32 + 16 * j + lr) * 64 + 8 * lg;
                kn[j][0] = *reinterpret_cast<const f16x8*>(kp);
                kn[j][1] = *reinterpret_cast<const f16x8*>(kp + 32);
            }
        }
        // online softmax (Q pre-scaled; no *0.125 here)
#pragma unroll
        for (int qt = 0; qt < 2; ++qt) {
            int qr = q0 + 16 * qt + lr;
            float sv[2][4];
            float mx = -1e30f;
#pragma unroll
            for (int j = 0; j < 2; ++j)
#pragma unroll
                for (int r = 0; r < 4; ++r) {
                    int kc = kk0 + 16 * j + 4 * lg + r;
                    float v = st[qt][j][r];
                    if (kc > qr || kc >= len) v = -1e30f;
                    sv[j][r] = v;
                    mx = fmaxf(mx, v);
                }
            mx = fmaxf(mx, __shfl_xor(mx, 16, 64));
            mx = fmaxf(mx, __shfl_xor(mx, 32, 64));
            float mnew = fmaxf(mrun[qt], mx);
            float al = __expf(mrun[qt] - mnew);
            mrun[qt] = mnew;
            float rs = 0.f;
            f16x4 pk0, pk1;
#pragma unroll
            for (int r = 0; r < 4; ++r) {
                float p0 = __expf(sv[0][r] - mnew);
                float p1 = __expf(sv[1][r] - mnew);
                rs += p0 + p1;
                pk0[r] = (f16)p0;
                pk1[r] = (f16)p1;
            }
            rs += __shfl_xor(rs, 16, 64);
            rs += __shfl_xor(rs, 32, 64);
            lrun[qt] = lrun[qt] * al + rs;
            *reinterpret_cast<f16x4*>(&pl[qt][lr][4 * lg])      = pk0;
            *reinterpret_cast<f16x4*>(&pl[qt][lr][16 + 4 * lg]) = pk1;
#pragma unroll
            for (int dt = 0; dt < 4; ++dt)
#pragma unroll
                for (int r = 0; r < 4; ++r) oacc[qt][dt][r] *= al;
        }
        __syncthreads();
        f16x8 pa0 = *reinterpret_cast<const f16x8*>(&pl[0][lr][8 * lg]);
        f16x8 pa1 = *reinterpret_cast<const f16x8*>(&pl[1][lr][8 * lg]);
#pragma unroll
        for (int dt = 0; dt < 4; ++dt) {
            oacc[0][dt] = MFMA16(vf[dt], pa0, oacc[0][dt]);
            oacc[1][dt] = MFMA16(vf[dt], pa1, oacc[1][dt]);
        }
        __syncthreads();
#pragma unroll
        for (int j = 0; j < 2; ++j) {
            kf[j][0] = kn[j][0];
            kf[j][1] = kn[j][1];
        }
    }
    // store: O[q=lr][d=16dt+4lg+r], vectorized 8B per (qt,dt)
#pragma unroll
    for (int qt = 0; qt < 2; ++qt) {
        int qr = q0 + 16 * qt + lr;
        if (qr >= len) continue;
        float linv = 1.f / lrun[qt];
        f16* orow = oh + (size_t)(s0 + qr) * 1024 + h * 64;
#pragma unroll
        for (int dt = 0; dt < 4; ++dt) {
            f16x4 ov;
#pragma unroll
            for (int r = 0; r < 4; ++r) ov[r] = (f16)(oacc[qt][dt][r] * linv);
            *reinterpret_cast<f16x4*>(orow + 16 * dt + 4 * lg) = ov;
        }
    }
}

// ---------------------------------------------------------------------------
extern "C" void kernel_launch(void* const* d_in, const int* in_sizes, int n_in,
                              void* d_out, int out_size, void* d_ws, size_t ws_size,
                              hipStream_t stream) {
    const float* x    = (const float*)d_in[0];
    const float* Wqkv = (const float*)d_in[1];
    const float* bqkv = (const float*)d_in[2];
    const float* Wo   = (const float*)d_in[3];
    const float* bo   = (const float*)d_in[4];
    const int*   cu   = (const int*)d_in[5];

    const int Dm = 1024;
    int T  = in_sizes[0] / Dm;
    int Bn = in_sizes[5] - 1;
    int Spad = 1024;  // max_seqlen

    auto al = [](size_t v) { return (v + 255) & ~(size_t)255; };
    char* w = (char*)d_ws;
    size_t off = 0;
    f16* xh     = (f16*)(w + off); off = al(off + (size_t)2 * T * 1024);
    f16* qkvh   = (f16*)(w + off); off = al(off + (size_t)2 * T * 3072);
    f16* wqkvT  = (f16*)(w + off); off = al(off + (size_t)2 * 3072 * 1024);
    f16* woT    = (f16*)(w + off); off = al(off + (size_t)2 * 1024 * 1024);
    f16* qh2    = (f16*)(w + off); off = al(off + (size_t)2 * Bn * 16 * 64 * (size_t)Spad);
    f16* kh2    = (f16*)(w + off); off = al(off + (size_t)2 * Bn * 16 * 64 * (size_t)Spad);
    f16* vtp    = (f16*)(w + off); off = al(off + (size_t)2 * Bn * 16 * 64 * (size_t)Spad);
    f16* ohp    = (f16*)(w + off); off = al(off + (size_t)2 * T * 1024);
    (void)ws_size;

    {
        int n = T * 1024;
        cvt_x<<<(n / 4 + 255) / 256, 256, 0, stream>>>(x, xh, n);
    }
    wtrans2<<<768 + 256, 256, 0, stream>>>(Wqkv, Wo, wqkvT, woT);
    {
        int nbx = 3072 / BN, nby = (T + BM - 1) / BM;
        gemm_tile<<<nbx * nby, 256, 0, stream>>>(xh, wqkvT, bqkv, qkvh, nullptr, T, 3072, 1024, nbx);
    }
    rope_v<<<dim3((T + 63) / 64, 16), 256, 0, stream>>>(qkvh, cu, Bn, T, Spad, qh2, kh2, vtp);
    {
        int nq = Spad / 32;
        int ngrid = nq * 16 * Bn;
        attn_fwd<<<ngrid, 64, 0, stream>>>(qh2, kh2, vtp, cu, ohp, Spad, nq, Bn);
    }
    {
        int nbx = 1024 / BN, nby = (T + BM - 1) / BM;
        gemm_tile<<<nbx * nby, 256, 0, stream>>>(ohp, woT, bo, nullptr, (float*)d_out, T, 1024, 1024, nbx);
    }
}